// Round 4
// baseline (121927.710 us; speedup 1.0000x reference)
//
#include <hip/hip_runtime.h>

#define V_ 32000
#define E_ 300
#define H_ 512
#define B_ 512
#define L_ 64
#define T_ (B_*L_)      // 32768 steps per chain
#define NWG 32          // workgroups per chain
#define NTHR 256
#define SPIN_CAP 2000000  // ~0.5s worst case; real waits are ~µs. Sticky: fires once.

// d_ws layout (float indices):
//   u32 cnt[chain] at u32 index chain*32 (128B apart)
//   h exchange:  WS_HB_F(c) + buf*512 + j      (2 chains x 2 bufs x 512)
//   sampled h:   WS_HOUT_F + (c*B_ + s)*H_ + j (2 x 512 x 512 floats = 2MB)
#define WS_CNT_U32(c)  ((c)*32)
#define WS_HB_F(c)     (64 + (c)*1024)
#define WS_HOUT_F      (4096)
#define WS_NEED_BYTES  ((size_t)(WS_HOUT_F + 2*B_*H_) * 4)

__global__ __launch_bounds__(NTHR, 1)
void lstm_scan_kernel(const int* __restrict__ tok0, const int* __restrict__ tok1,
                      const float* __restrict__ emb, const float* __restrict__ Wih,
                      const float* __restrict__ Whh, const float* __restrict__ bih,
                      const float* __restrict__ bhh, float* ws)
{
    const int blk   = blockIdx.x;
    const int chain = blk >> 5;      // 0..1
    const int wg    = blk & 31;      // 0..31
    const int tid   = threadIdx.x;
    const int r     = tid >> 2;      // 0..63  local gate-row
    const int part  = tid & 3;       // 0..3   column quarter
    const int jj    = r >> 2;        // 0..15  local hidden unit
    const int g     = r & 3;         // 0..3   gate (i,f,g,o)
    const int j     = wg*16 + jj;    // global hidden unit
    const int row   = g*H_ + j;      // global gate row in [0,2048)

    __shared__ float x_lds[2][304];  // padded E (300 -> 304)
    __shared__ float h_lds[H_];
    __shared__ float gates_lds[64];
    __shared__ int   dead_lds;

    // ---- weights resident in registers ----
    float wh[128];
    {
        const float* p = Whh + (size_t)row*H_ + part*128;
        #pragma unroll
        for (int k = 0; k < 128; ++k) wh[k] = p[k];
    }
    float wi[76];
    {
        const float* p = Wih + (size_t)row*E_;
        #pragma unroll
        for (int k = 0; k < 76; ++k) {
            const int col = part*76 + k;
            wi[k] = (col < E_) ? p[col] : 0.f;
        }
    }
    const float bias = bih[row] + bhh[row];

    const int* tok = chain ? tok1 : tok0;
    unsigned* cnt  = (unsigned*)ws + WS_CNT_U32(chain);
    float*    hb   = ws + WS_HB_F(chain);
    float*    hout = ws + WS_HOUT_F;

    // ---- stage x(0); zero the pad lanes of both x buffers ----
    if (tid == 0) dead_lds = 0;
    if (tid < 4) { x_lds[0][300+tid] = 0.f; x_lds[1][300+tid] = 0.f; }
    if (tid < 75) {
        const float4 v = *(const float4*)(emb + (size_t)tok[0]*E_ + tid*4);
        *(float4*)&x_lds[0][tid*4] = v;
    }
    __syncthreads();

    float cst  = 0.f;   // cell state for hidden unit j (lanes tid<16 only)
    int   dead = 0;     // sticky give-up flag: converts any stall into a
                        // wrong-answer exit instead of a GPU hang

    for (int t = 0; t < T_; ++t) {
        const int cur = t & 1, nxt = cur ^ 1;

        // prefetch x(t+1) into registers (latency hidden under this whole step)
        float4 xn = make_float4(0.f, 0.f, 0.f, 0.f);
        if (tid < 75 && (t+1) < T_) {
            xn = *(const float4*)(emb + (size_t)tok[t+1]*E_ + tid*4);
        }

        // x-part of this thread's gate row (no recurrence dependency)
        float xd = 0.f;
        {
            const float* xp = &x_lds[cur][part*76];
            #pragma unroll
            for (int k = 0; k < 76; ++k) xd += wi[k]*xp[k];
        }

        // wait for h_t, gather it into LDS
        if (t > 0) {
            if (tid == 0 && !dead) {
                int polls = 0;
                while (__hip_atomic_load(cnt, __ATOMIC_ACQUIRE, __HIP_MEMORY_SCOPE_AGENT)
                       < (unsigned)(NWG*t)) {
                    __builtin_amdgcn_s_sleep(1);
                    if (++polls > SPIN_CAP) { dead_lds = 1; break; }
                }
            }
            __syncthreads();
            dead = dead_lds;
            const float* hsrc = hb + cur*H_;
            h_lds[tid]     = __hip_atomic_load(hsrc + tid,     __ATOMIC_RELAXED, __HIP_MEMORY_SCOPE_AGENT);
            h_lds[tid+256] = __hip_atomic_load(hsrc + tid+256, __ATOMIC_RELAXED, __HIP_MEMORY_SCOPE_AGENT);
        } else {
            h_lds[tid] = 0.f; h_lds[tid+256] = 0.f;
        }
        __syncthreads();

        // h-part: 128 register-weight FMAs against LDS-broadcast h
        float d = xd;
        {
            const float* hp = &h_lds[part*128];
            #pragma unroll
            for (int k = 0; k < 128; ++k) d += wh[k]*hp[k];
        }
        // reduce the 4 column-quarters of this row
        d += __shfl_xor(d, 1);
        d += __shfl_xor(d, 2);
        if (part == 0) gates_lds[r] = d + bias;
        __syncthreads();

        // elementwise LSTM cell on 16 lanes of wave 0 (tid == jj)
        if (tid < 16) {
            const float gi = gates_lds[tid*4+0];
            const float gf = gates_lds[tid*4+1];
            const float gg = gates_lds[tid*4+2];
            const float go = gates_lds[tid*4+3];
            const float ai = 1.f/(1.f + expf(-gi));
            const float af = 1.f/(1.f + expf(-gf));
            const float ag = tanhf(gg);
            const float ao = 1.f/(1.f + expf(-go));
            cst = af*cst + ai*ag;
            const float hnew = ao*tanhf(cst);
            __hip_atomic_store(hb + nxt*H_ + wg*16 + tid, hnew,
                               __ATOMIC_RELAXED, __HIP_MEMORY_SCOPE_AGENT);
            if (((t+1) & 63) == 0) {
                hout[((size_t)chain*B_ + (t>>6))*H_ + wg*16 + tid] = hnew;
            }
        }
        // release: same wave as the h stores above -> vmcnt(0) covers them
        if (tid == 0) {
            __hip_atomic_fetch_add(cnt, 1u, __ATOMIC_RELEASE, __HIP_MEMORY_SCOPE_AGENT);
        }

        // commit prefetched x(t+1) into the other LDS buffer
        if (tid < 75 && (t+1) < T_) {
            *(float4*)&x_lds[nxt][tid*4] = xn;
        }
        __syncthreads();
    }
}

__global__ void pred_kernel(const float* __restrict__ ws, float* __restrict__ out)
{
    const int b    = blockIdx.x;
    const int lane = threadIdx.x;
    const float* h1 = ws + WS_HOUT_F + (size_t)b*H_;
    const float* h2 = ws + WS_HOUT_F + ((size_t)B_ + b)*H_;
    float s = 0.f;
    for (int k = lane; k < H_; k += 64) s += fabsf(h1[k] - h2[k]);
    #pragma unroll
    for (int off = 32; off; off >>= 1) s += __shfl_down(s, off);
    if (lane == 0) out[b] = expf(-s);
}

// Fallback if ws_size is too small for the layout: write a clearly-wrong,
// clearly-identifiable value without touching any OOB memory.
__global__ void ws_too_small_kernel(float* __restrict__ out)
{
    out[blockIdx.x * 64 + threadIdx.x] = -1.0f;
}

extern "C" void kernel_launch(void* const* d_in, const int* in_sizes, int n_in,
                              void* d_out, int out_size, void* d_ws, size_t ws_size,
                              hipStream_t stream)
{
    const int*   tok0 = (const int*)d_in[0];
    const int*   tok1 = (const int*)d_in[1];
    const float* emb  = (const float*)d_in[2];
    const float* Wih  = (const float*)d_in[3];
    const float* Whh  = (const float*)d_in[4];
    const float* bih  = (const float*)d_in[5];
    const float* bhh  = (const float*)d_in[6];
    float* ws  = (float*)d_ws;
    float* out = (float*)d_out;

    if (ws_size < WS_NEED_BYTES) {
        // Diagnostic path: no scan, no OOB reads/writes, visible wrong answer.
        ws_too_small_kernel<<<dim3(B_/64), dim3(64), 0, stream>>>(out);
        return;
    }

    // reset counters + h exchange buffers (NOT the hout region)
    hipMemsetAsync(d_ws, 0, 16384, stream);

    // 64 blocks on 256 CUs: co-resident with a plain launch; the sync is a
    // hand-rolled arrival counter (no grid.sync()), so cooperative launch
    // (which failed silently in round 0) is not needed.
    lstm_scan_kernel<<<dim3(2*NWG), dim3(NTHR), 0, stream>>>(
        tok0, tok1, emb, Wih, Whh, bih, bhh, ws);

    pred_kernel<<<B_, 64, 0, stream>>>(ws, out);
}